// Round 4
// baseline (571.638 us; speedup 1.0000x reference)
//
#include <hip/hip_runtime.h>
#include <hip/hip_bf16.h>
#include <stdint.h>

typedef __hip_bfloat16 bf16;
typedef __hip_bfloat162 bf162;

typedef __attribute__((ext_vector_type(8))) short short8;   // 8 bf16 = 4 VGPRs
typedef __attribute__((ext_vector_type(4))) float floatx4;  // MFMA accumulator

#define BSH   8        // bucket = 256 nodes
#define BSZ   256
#define CHUNK 8192     // edges per sort block
#define NBMAX 512      // max buckets supported (N <= 131072)
#define ASTRIDE 136    // LDS A-tile row stride in bf16 (272 B: 16B-aligned, <=2-way banks)

// ---------------- helpers ----------------

__device__ __forceinline__ float2 load2f(const bf16* __restrict__ p) {
    const unsigned int u = *(const unsigned int*)p;
    return make_float2(__uint_as_float((u & 0xffffu) << 16),
                       __uint_as_float(u & 0xffff0000u));
}

// ---------------- prep: fp32 -> bf16 ----------------

__global__ __launch_bounds__(256)
void cvt_kernel(const float* __restrict__ x, bf16* __restrict__ y, int n4) {
    int i = blockIdx.x * 256 + threadIdx.x;
    if (i < n4) {
        float4 v = ((const float4*)x)[i];
        bf162 a, b;
        a.x = __float2bfloat16(v.x); a.y = __float2bfloat16(v.y);
        b.x = __float2bfloat16(v.z); b.y = __float2bfloat16(v.w);
        ((bf162*)y)[i * 2]     = a;
        ((bf162*)y)[i * 2 + 1] = b;
    }
}

// weights pre-swizzled to B-fragment layout for mfma_f32_16x16x32_bf16:
// wsw[((kt*8+ct)*64+lane)*8 + j] = W[kt*32 + (lane>>4)*8 + j][ct*16 + (lane&15)]
// where W = concat_k(w_rel, w_root), 256x128 row-major.
__global__ __launch_bounds__(256)
void prep_w_kernel(const float* __restrict__ wrel, const float* __restrict__ wroot,
                   bf16* __restrict__ wsw) {
    int t = blockIdx.x * 256 + threadIdx.x;       // 0..4095
    if (t >= 4096) return;
    const int lane = t & 63;
    const int ct   = (t >> 6) & 7;
    const int kt   = t >> 9;
    const int kbase = kt * 32 + (lane >> 4) * 8;
    const int n     = ct * 16 + (lane & 15);
    bf16* q = wsw + (size_t)t * 8;
#pragma unroll
    for (int j = 0; j < 8; ++j) {
        const int k = kbase + j;
        const float v = (k < 128) ? wrel[k * 128 + n] : wroot[(k - 128) * 128 + n];
        q[j] = __float2bfloat16(v);
    }
}

// ---------------- CSR build: two-level counting sort ----------------

__global__ __launch_bounds__(256)
void bhist_kernel(const int* __restrict__ dst, int* __restrict__ T,
                  int E, int NB, int GB) {
    __shared__ int lh[NBMAX];
    const int b = blockIdx.x;
    for (int u = threadIdx.x; u < NB; u += 256) lh[u] = 0;
    __syncthreads();
    const int beg = b * CHUNK, end = min(beg + CHUNK, E);
    for (int e = beg + threadIdx.x; e < end; e += 256)
        atomicAdd(&lh[dst[e] >> BSH], 1);
    __syncthreads();
    for (int u = threadIdx.x; u < NB; u += 256)
        T[u * GB + b] = lh[u];
}

__global__ __launch_bounds__(256)
void scan1_kernel(const int* __restrict__ deg, int* __restrict__ rp,
                  int* __restrict__ bsum, int n) {
    __shared__ int s[256];
    const int tid = threadIdx.x;
    const int i = blockIdx.x * 256 + tid;
    const int d = (i < n) ? deg[i] : 0;
    s[tid] = d;
    __syncthreads();
    for (int off = 1; off < 256; off <<= 1) {
        int u = (tid >= off) ? s[tid - off] : 0;
        __syncthreads();
        s[tid] += u;
        __syncthreads();
    }
    if (i < n) rp[i] = s[tid] - d;
    if (tid == 255) bsum[blockIdx.x] = s[255];
}

__global__ __launch_bounds__(512)
void scan2_kernel(int* __restrict__ bsum, int G) {
    __shared__ int s[512];
    const int tid = threadIdx.x;
    const int d = (tid < G) ? bsum[tid] : 0;
    s[tid] = d;
    __syncthreads();
    for (int off = 1; off < 512; off <<= 1) {
        int u = (tid >= off) ? s[tid - off] : 0;
        __syncthreads();
        s[tid] += u;
        __syncthreads();
    }
    if (tid < G) bsum[tid] = s[tid] - d;
}

__global__ __launch_bounds__(256)
void scan3_kernel(int* __restrict__ rp, const int* __restrict__ bsum, int n) {
    const int i = blockIdx.x * 256 + threadIdx.x;
    if (i < n) rp[i] += bsum[blockIdx.x];
}

__global__ __launch_bounds__(256)
void bscatter_kernel(const int* __restrict__ src, const int* __restrict__ dst,
                     const int* __restrict__ T, int* __restrict__ ebuf,
                     int E, int NB, int GB) {
    __shared__ int lofs[NBMAX];
    const int b = blockIdx.x;
    for (int u = threadIdx.x; u < NB; u += 256)
        lofs[u] = T[u * GB + b];
    __syncthreads();
    const int beg = b * CHUNK, end = min(beg + CHUNK, E);
    for (int e = beg + threadIdx.x; e < end; e += 256) {
        const int d = dst[e];
        const int u = d >> BSH;
        const int pos = atomicAdd(&lofs[u], 1);
        ebuf[pos] = (src[e] << BSH) | (d & (BSZ - 1));
    }
}

__global__ __launch_bounds__(256)
void bbuild_kernel(const int* __restrict__ T, const int* __restrict__ ebuf,
                   int* __restrict__ rp, int* __restrict__ col,
                   int E, int N, int NB, int GB) {
    __shared__ int s[256];
    __shared__ int lrank[256];
    const int u = blockIdx.x;
    const int tid = threadIdx.x;
    const int beg = T[u * GB];
    const int end = (u + 1 < NB) ? T[(u + 1) * GB] : E;

    lrank[tid] = 0;
    __syncthreads();
    for (int e = beg + tid; e < end; e += 256)
        atomicAdd(&lrank[ebuf[e] & (BSZ - 1)], 1);
    __syncthreads();
    const int cntv = lrank[tid];
    s[tid] = cntv;
    __syncthreads();
    for (int off = 1; off < 256; off <<= 1) {
        int v = (tid >= off) ? s[tid - off] : 0;
        __syncthreads();
        s[tid] += v;
        __syncthreads();
    }
    const int excl = s[tid] - cntv;
    const int node = u * BSZ + tid;
    if (node < N) rp[node] = beg + excl;
    if (u == NB - 1 && tid == 0) rp[N] = E;
    lrank[tid] = beg + excl;
    __syncthreads();
    for (int e = beg + tid; e < end; e += 256) {
        const int p = ebuf[e];
        const int pos = atomicAdd(&lrank[p & (BSZ - 1)], 1);
        col[pos] = p >> BSH;
    }
}

// ---------------- fused layer: aggregate -> LDS -> dual MFMA GEMM ----------------
// block = 256 threads (4 waves) = 64 nodes.
// phase 1: wave w aggregates nodes node0+w*16..+15 (lane owns 2 features,
//          8-edge unroll) into LDS A-tile (row stride 272 B).
// phase 2: out = [Atile | h] @ Wsw + b (+relu); kt 0..3 A-frags from LDS,
//          kt 4..7 root-frags preloaded from global before phase 1 (overlap).

template <bool RELU, typename OT>
__global__ __launch_bounds__(256)
void fused_layer_kernel(const bf16* __restrict__ h, const int* __restrict__ rp,
                        const int* __restrict__ col, const bf16* __restrict__ wsw,
                        const float* __restrict__ bias, OT* __restrict__ out, int N) {
    __shared__ bf16 As[64 * ASTRIDE];
    const int tid  = threadIdx.x;
    const int lane = tid & 63;
    const int wave = tid >> 6;
    const int l15  = lane & 15;
    const int quad = lane >> 4;
    const int node0 = blockIdx.x * 64;

    // root fragments (kt 4..7), issued before the gather phase for overlap
    const int row_a = node0 + wave * 16 + l15;
    const bool rowok = row_a < N;
    short8 rootfrag[4];
#pragma unroll
    for (int kt = 0; kt < 4; ++kt) {
        rootfrag[kt] = (short8){0, 0, 0, 0, 0, 0, 0, 0};
        if (rowok)
            rootfrag[kt] = *(const short8*)(h + (size_t)row_a * 128 + kt * 32 + quad * 8);
    }

    // ---- phase 1: aggregate 16 nodes per wave ----
    const int f = lane * 2;
    for (int i = 0; i < 16; ++i) {
        const int node = node0 + wave * 16 + i;
        float2 acc = make_float2(0.f, 0.f);
        if (node < N) {
            const int beg = rp[node], endd = rp[node + 1];
            int e = beg;
            for (; e + 8 <= endd; e += 8) {
                const int s0 = col[e],     s1 = col[e + 1], s2 = col[e + 2], s3 = col[e + 3];
                const int s4 = col[e + 4], s5 = col[e + 5], s6 = col[e + 6], s7 = col[e + 7];
                const float2 a0 = load2f(h + (size_t)s0 * 128 + f);
                const float2 a1 = load2f(h + (size_t)s1 * 128 + f);
                const float2 a2 = load2f(h + (size_t)s2 * 128 + f);
                const float2 a3 = load2f(h + (size_t)s3 * 128 + f);
                const float2 a4 = load2f(h + (size_t)s4 * 128 + f);
                const float2 a5 = load2f(h + (size_t)s5 * 128 + f);
                const float2 a6 = load2f(h + (size_t)s6 * 128 + f);
                const float2 a7 = load2f(h + (size_t)s7 * 128 + f);
                acc.x += ((a0.x + a1.x) + (a2.x + a3.x)) + ((a4.x + a5.x) + (a6.x + a7.x));
                acc.y += ((a0.y + a1.y) + (a2.y + a3.y)) + ((a4.y + a5.y) + (a6.y + a7.y));
            }
            for (; e + 2 <= endd; e += 2) {
                const int s0 = col[e], s1 = col[e + 1];
                const float2 a0 = load2f(h + (size_t)s0 * 128 + f);
                const float2 a1 = load2f(h + (size_t)s1 * 128 + f);
                acc.x += a0.x + a1.x;
                acc.y += a0.y + a1.y;
            }
            if (e < endd) {
                const float2 a0 = load2f(h + (size_t)col[e] * 128 + f);
                acc.x += a0.x;
                acc.y += a0.y;
            }
        }
        bf162 o;
        o.x = __float2bfloat16(acc.x);
        o.y = __float2bfloat16(acc.y);
        *(bf162*)(As + (wave * 16 + i) * ASTRIDE + f) = o;
    }
    __syncthreads();

    // ---- phase 2: dual GEMM ----
    floatx4 acc[8];
#pragma unroll
    for (int ct = 0; ct < 8; ++ct) acc[ct] = (floatx4){0.f, 0.f, 0.f, 0.f};

#pragma unroll
    for (int kt = 0; kt < 8; ++kt) {
        short8 afrag;
        if (kt < 4)
            afrag = *(const short8*)(As + (wave * 16 + l15) * ASTRIDE + kt * 32 + quad * 8);
        else
            afrag = rootfrag[kt - 4];
#pragma unroll
        for (int ct = 0; ct < 8; ++ct) {
            const short8 bfrag = *(const short8*)(wsw + (size_t)((kt * 8 + ct) * 64 + lane) * 8);
            acc[ct] = __builtin_amdgcn_mfma_f32_16x16x32_bf16(afrag, bfrag, acc[ct], 0, 0, 0);
        }
    }

    const int row_o = node0 + wave * 16 + quad * 4;
#pragma unroll
    for (int ct = 0; ct < 8; ++ct) {
        const int colc = ct * 16 + l15;
        const float bv = bias[colc];
#pragma unroll
        for (int r = 0; r < 4; ++r) {
            const int row = row_o + r;
            if (row < N) {
                float v = acc[ct][r] + bv;
                if (RELU) v = fmaxf(v, 0.f);
                if constexpr (sizeof(OT) == 2)
                    ((bf16*)out)[(size_t)row * 128 + colc] = __float2bfloat16(v);
                else
                    ((float*)out)[(size_t)row * 128 + colc] = v;
            }
        }
    }
}

// ---------------- launch ----------------

extern "C" void kernel_launch(void* const* d_in, const int* in_sizes, int n_in,
                              void* d_out, int out_size, void* d_ws, size_t ws_size,
                              hipStream_t stream) {
    const float* x       = (const float*)d_in[0];
    const int*   ei      = (const int*)d_in[1];
    const float* w_rel1  = (const float*)d_in[2];
    const float* w_root1 = (const float*)d_in[3];
    const float* b1      = (const float*)d_in[4];
    const float* w_rel2  = (const float*)d_in[5];
    const float* w_root2 = (const float*)d_in[6];
    const float* b2      = (const float*)d_in[7];
    const float* w_rel3  = (const float*)d_in[8];
    const float* w_root3 = (const float*)d_in[9];
    const float* b3      = (const float*)d_in[10];
    float* out = (float*)d_out;

    const int N = in_sizes[0] / 128;
    const int E = in_sizes[1] / 2;
    const int* src = ei;
    const int* dst = ei + E;

    // workspace layout (~65 MB)
    char* w = (char*)d_ws;
    auto alloc = [&](size_t bytes) {
        char* p = w;
        w += (bytes + 255) & ~(size_t)255;
        return p;
    };
    int*  col  = (int*)alloc((size_t)E * 4);            // 6.4 MB
    int*  rp   = (int*)alloc((size_t)(N + 1) * 4);      // 0.4 MB
    int*  ebuf = (int*)alloc((size_t)E * 4);            // 6.4 MB
    bf16* h1   = (bf16*)alloc((size_t)N * 128 * 2);     // 25.6 MB
    bf16* xbf  = (bf16*)alloc((size_t)N * 128 * 2);     // 25.6 MB (reused as h2)
    bf16* wsw1 = (bf16*)alloc(32768 * 2);               // 64 KB
    bf16* wsw2 = (bf16*)alloc(32768 * 2);
    bf16* wsw3 = (bf16*)alloc(32768 * 2);
    bf16* h2   = xbf;   // layer-2 output overwrites xbf (last read: layer-1 fused)
    // CSR-build scratch aliases h1 (written only after the build completes):
    int*  T    = (int*)h1;                  // NB*GB ints (~306 KB)
    int*  bsum = (int*)(h1 + 1024 * 1024);  // scan partials, past T

    const int NB = (N + BSZ - 1) / BSZ;        // 391 buckets
    const int GB = (E + CHUNK - 1) / CHUNK;    // 196 sort blocks
    const int nT = NB * GB;                    // 76,636
    const int scanTBlocks = (nT + 255) / 256;  // 300 <= 512

    const int layerBlocks = (N + 63) / 64;
    const int cvtBlocks   = (N * 32 + 255) / 256;

    // prep: x -> bf16, weights -> swizzled bf16 B-fragments
    cvt_kernel<<<cvtBlocks, 256, 0, stream>>>(x, xbf, N * 32);
    prep_w_kernel<<<16, 256, 0, stream>>>(w_rel1, w_root1, wsw1);
    prep_w_kernel<<<16, 256, 0, stream>>>(w_rel2, w_root2, wsw2);
    prep_w_kernel<<<16, 256, 0, stream>>>(w_rel3, w_root3, wsw3);

    // CSR by dst: two-level counting sort (no global atomics, no memsets)
    bhist_kernel<<<GB, 256, 0, stream>>>(dst, T, E, NB, GB);
    scan1_kernel<<<scanTBlocks, 256, 0, stream>>>(T, T, bsum, nT);
    scan2_kernel<<<1, 512, 0, stream>>>(bsum, scanTBlocks);
    scan3_kernel<<<scanTBlocks, 256, 0, stream>>>(T, bsum, nT);
    bscatter_kernel<<<GB, 256, 0, stream>>>(src, dst, T, ebuf, E, NB, GB);
    bbuild_kernel<<<NB, 256, 0, stream>>>(T, ebuf, rp, col, E, N, NB, GB);

    // fused layers
    fused_layer_kernel<true, bf16><<<layerBlocks, 256, 0, stream>>>(xbf, rp, col, wsw1, b1, h1, N);
    fused_layer_kernel<true, bf16><<<layerBlocks, 256, 0, stream>>>(h1, rp, col, wsw2, b2, h2, N);
    fused_layer_kernel<false, float><<<layerBlocks, 256, 0, stream>>>(h2, rp, col, wsw3, b3, out, N);
}

// Round 5
// 485.087 us; speedup vs baseline: 1.1784x; 1.1784x over previous
//
#include <hip/hip_runtime.h>
#include <hip/hip_bf16.h>
#include <stdint.h>

typedef __hip_bfloat16 bf16;
typedef __hip_bfloat162 bf162;

typedef __attribute__((ext_vector_type(8))) short short8;   // 8 bf16 = 4 VGPRs
typedef __attribute__((ext_vector_type(4))) float floatx4;  // MFMA accumulator

#define BSH   8        // bucket = 256 nodes
#define BSZ   256
#define CHUNK 8192     // edges per sort block
#define NBMAX 512      // max buckets supported (N <= 131072)

// ---------------- helpers ----------------

__device__ __forceinline__ float2 load2f(const bf16* __restrict__ p) {
    const unsigned int u = *(const unsigned int*)p;
    return make_float2(__uint_as_float((u & 0xffffu) << 16),
                       __uint_as_float(u & 0xffff0000u));
}

// ---------------- prep: fp32 -> bf16 ----------------

__global__ __launch_bounds__(256)
void cvt_kernel(const float* __restrict__ x, bf16* __restrict__ y, int n4) {
    int i = blockIdx.x * 256 + threadIdx.x;
    if (i < n4) {
        float4 v = ((const float4*)x)[i];
        bf162 a, b;
        a.x = __float2bfloat16(v.x); a.y = __float2bfloat16(v.y);
        b.x = __float2bfloat16(v.z); b.y = __float2bfloat16(v.w);
        ((bf162*)y)[i * 2]     = a;
        ((bf162*)y)[i * 2 + 1] = b;
    }
}

// weights pre-swizzled to B-fragment layout for mfma_f32_16x16x32_bf16:
// wsw[((kt*8+ct)*64+lane)*8 + j] = W[kt*32 + (lane>>4)*8 + j][ct*16 + (lane&15)]
// where W = concat_k(w_rel, w_root), 256x128 row-major.
__global__ __launch_bounds__(256)
void prep_w_kernel(const float* __restrict__ wrel, const float* __restrict__ wroot,
                   bf16* __restrict__ wsw) {
    int t = blockIdx.x * 256 + threadIdx.x;       // 0..4095
    if (t >= 4096) return;
    const int lane = t & 63;
    const int ct   = (t >> 6) & 7;
    const int kt   = t >> 9;
    const int kbase = kt * 32 + (lane >> 4) * 8;
    const int n     = ct * 16 + (lane & 15);
    bf16* q = wsw + (size_t)t * 8;
#pragma unroll
    for (int j = 0; j < 8; ++j) {
        const int k = kbase + j;
        const float v = (k < 128) ? wrel[k * 128 + n] : wroot[(k - 128) * 128 + n];
        q[j] = __float2bfloat16(v);
    }
}

// ---------------- CSR build: two-level counting sort ----------------

__global__ __launch_bounds__(256)
void bhist_kernel(const int* __restrict__ dst, int* __restrict__ T,
                  int E, int NB, int GB) {
    __shared__ int lh[NBMAX];
    const int b = blockIdx.x;
    for (int u = threadIdx.x; u < NB; u += 256) lh[u] = 0;
    __syncthreads();
    const int beg = b * CHUNK, end = min(beg + CHUNK, E);
    for (int e = beg + threadIdx.x; e < end; e += 256)
        atomicAdd(&lh[dst[e] >> BSH], 1);
    __syncthreads();
    for (int u = threadIdx.x; u < NB; u += 256)
        T[u * GB + b] = lh[u];
}

__global__ __launch_bounds__(256)
void scan1_kernel(const int* __restrict__ deg, int* __restrict__ rp,
                  int* __restrict__ bsum, int n) {
    __shared__ int s[256];
    const int tid = threadIdx.x;
    const int i = blockIdx.x * 256 + tid;
    const int d = (i < n) ? deg[i] : 0;
    s[tid] = d;
    __syncthreads();
    for (int off = 1; off < 256; off <<= 1) {
        int u = (tid >= off) ? s[tid - off] : 0;
        __syncthreads();
        s[tid] += u;
        __syncthreads();
    }
    if (i < n) rp[i] = s[tid] - d;
    if (tid == 255) bsum[blockIdx.x] = s[255];
}

__global__ __launch_bounds__(512)
void scan2_kernel(int* __restrict__ bsum, int G) {
    __shared__ int s[512];
    const int tid = threadIdx.x;
    const int d = (tid < G) ? bsum[tid] : 0;
    s[tid] = d;
    __syncthreads();
    for (int off = 1; off < 512; off <<= 1) {
        int u = (tid >= off) ? s[tid - off] : 0;
        __syncthreads();
        s[tid] += u;
        __syncthreads();
    }
    if (tid < G) bsum[tid] = s[tid] - d;
}

__global__ __launch_bounds__(256)
void scan3_kernel(int* __restrict__ rp, const int* __restrict__ bsum, int n) {
    const int i = blockIdx.x * 256 + threadIdx.x;
    if (i < n) rp[i] += bsum[blockIdx.x];
}

__global__ __launch_bounds__(256)
void bscatter_kernel(const int* __restrict__ src, const int* __restrict__ dst,
                     const int* __restrict__ T, int* __restrict__ ebuf,
                     int E, int NB, int GB) {
    __shared__ int lofs[NBMAX];
    const int b = blockIdx.x;
    for (int u = threadIdx.x; u < NB; u += 256)
        lofs[u] = T[u * GB + b];
    __syncthreads();
    const int beg = b * CHUNK, end = min(beg + CHUNK, E);
    for (int e = beg + threadIdx.x; e < end; e += 256) {
        const int d = dst[e];
        const int u = d >> BSH;
        const int pos = atomicAdd(&lofs[u], 1);
        ebuf[pos] = (src[e] << BSH) | (d & (BSZ - 1));
    }
}

__global__ __launch_bounds__(256)
void bbuild_kernel(const int* __restrict__ T, const int* __restrict__ ebuf,
                   int* __restrict__ rp, int* __restrict__ col,
                   int E, int N, int NB, int GB) {
    __shared__ int s[256];
    __shared__ int lrank[256];
    const int u = blockIdx.x;
    const int tid = threadIdx.x;
    const int beg = T[u * GB];
    const int end = (u + 1 < NB) ? T[(u + 1) * GB] : E;

    lrank[tid] = 0;
    __syncthreads();
    for (int e = beg + tid; e < end; e += 256)
        atomicAdd(&lrank[ebuf[e] & (BSZ - 1)], 1);
    __syncthreads();
    const int cntv = lrank[tid];
    s[tid] = cntv;
    __syncthreads();
    for (int off = 1; off < 256; off <<= 1) {
        int v = (tid >= off) ? s[tid - off] : 0;
        __syncthreads();
        s[tid] += v;
        __syncthreads();
    }
    const int excl = s[tid] - cntv;
    const int node = u * BSZ + tid;
    if (node < N) rp[node] = beg + excl;
    if (u == NB - 1 && tid == 0) rp[N] = E;
    lrank[tid] = beg + excl;
    __syncthreads();
    for (int e = beg + tid; e < end; e += 256) {
        const int p = ebuf[e];
        const int pos = atomicAdd(&lrank[p & (BSZ - 1)], 1);
        col[pos] = p >> BSH;
    }
}

// ---------------- aggregation (CSR, atomic-free, bf16) ----------------
// one wave per node (zero intra-wave divergence); lane owns 2 features;
// 8-edge unroll = 8 independent 256B row-gathers in flight per wave (MLP).

__global__ __launch_bounds__(256)
void agg_kernel(const bf16* __restrict__ h, const int* __restrict__ rp,
                const int* __restrict__ col, bf16* __restrict__ agg, int N) {
    const int lane = threadIdx.x & 63;
    const int wid  = threadIdx.x >> 6;
    const int node = blockIdx.x * 4 + wid;
    if (node >= N) return;
    const int beg = rp[node], end = rp[node + 1];
    const int f = lane * 2;
    float2 acc = make_float2(0.f, 0.f);
    int e = beg;
    for (; e + 8 <= end; e += 8) {
        const int s0 = col[e],     s1 = col[e + 1], s2 = col[e + 2], s3 = col[e + 3];
        const int s4 = col[e + 4], s5 = col[e + 5], s6 = col[e + 6], s7 = col[e + 7];
        const float2 a0 = load2f(h + (size_t)s0 * 128 + f);
        const float2 a1 = load2f(h + (size_t)s1 * 128 + f);
        const float2 a2 = load2f(h + (size_t)s2 * 128 + f);
        const float2 a3 = load2f(h + (size_t)s3 * 128 + f);
        const float2 a4 = load2f(h + (size_t)s4 * 128 + f);
        const float2 a5 = load2f(h + (size_t)s5 * 128 + f);
        const float2 a6 = load2f(h + (size_t)s6 * 128 + f);
        const float2 a7 = load2f(h + (size_t)s7 * 128 + f);
        acc.x += ((a0.x + a1.x) + (a2.x + a3.x)) + ((a4.x + a5.x) + (a6.x + a7.x));
        acc.y += ((a0.y + a1.y) + (a2.y + a3.y)) + ((a4.y + a5.y) + (a6.y + a7.y));
    }
    for (; e + 2 <= end; e += 2) {
        const int s0 = col[e], s1 = col[e + 1];
        const float2 a0 = load2f(h + (size_t)s0 * 128 + f);
        const float2 a1 = load2f(h + (size_t)s1 * 128 + f);
        acc.x += a0.x + a1.x;
        acc.y += a0.y + a1.y;
    }
    if (e < end) {
        const float2 a0 = load2f(h + (size_t)col[e] * 128 + f);
        acc.x += a0.x;
        acc.y += a0.y;
    }
    bf162 o;
    o.x = __float2bfloat16(acc.x);
    o.y = __float2bfloat16(acc.y);
    *(bf162*)(agg + (size_t)node * 128 + f) = o;
}

// ---------------- MFMA dual GEMM: out = [agg|h] @ Wsw + b (+relu) ----------------

template <bool RELU, typename OT>
__global__ __launch_bounds__(256)
void mfma_gemm_kernel(const bf16* __restrict__ Aagg, const bf16* __restrict__ Hroot,
                      const bf16* __restrict__ wsw, const float* __restrict__ bias,
                      OT* __restrict__ out, int M) {
    const int tid  = threadIdx.x;
    const int lane = tid & 63;
    const int wave = tid >> 6;
    const int l15  = lane & 15;
    const int quad = lane >> 4;

    const int row_a = blockIdx.x * 64 + wave * 16 + l15;
    const bool rowok = row_a < M;

    floatx4 acc[8];
#pragma unroll
    for (int ct = 0; ct < 8; ++ct) acc[ct] = (floatx4){0.f, 0.f, 0.f, 0.f};

#pragma unroll
    for (int kt = 0; kt < 8; ++kt) {
        const bf16* Abase = (kt < 4) ? Aagg : Hroot;
        const int k0 = (kt & 3) * 32 + quad * 8;
        short8 afrag = (short8){0, 0, 0, 0, 0, 0, 0, 0};
        if (rowok) afrag = *(const short8*)(Abase + (size_t)row_a * 128 + k0);
#pragma unroll
        for (int ct = 0; ct < 8; ++ct) {
            const short8 bfrag = *(const short8*)(wsw + (size_t)((kt * 8 + ct) * 64 + lane) * 8);
            acc[ct] = __builtin_amdgcn_mfma_f32_16x16x32_bf16(afrag, bfrag, acc[ct], 0, 0, 0);
        }
    }

    const int row_o = blockIdx.x * 64 + wave * 16 + quad * 4;
#pragma unroll
    for (int ct = 0; ct < 8; ++ct) {
        const int colc = ct * 16 + l15;
        const float bv = bias[colc];
#pragma unroll
        for (int r = 0; r < 4; ++r) {
            const int row = row_o + r;
            if (row < M) {
                float v = acc[ct][r] + bv;
                if (RELU) v = fmaxf(v, 0.f);
                if constexpr (sizeof(OT) == 2)
                    ((bf16*)out)[(size_t)row * 128 + colc] = __float2bfloat16(v);
                else
                    ((float*)out)[(size_t)row * 128 + colc] = v;
            }
        }
    }
}

// ---------------- launch ----------------

extern "C" void kernel_launch(void* const* d_in, const int* in_sizes, int n_in,
                              void* d_out, int out_size, void* d_ws, size_t ws_size,
                              hipStream_t stream) {
    const float* x       = (const float*)d_in[0];
    const int*   ei      = (const int*)d_in[1];
    const float* w_rel1  = (const float*)d_in[2];
    const float* w_root1 = (const float*)d_in[3];
    const float* b1      = (const float*)d_in[4];
    const float* w_rel2  = (const float*)d_in[5];
    const float* w_root2 = (const float*)d_in[6];
    const float* b2      = (const float*)d_in[7];
    const float* w_rel3  = (const float*)d_in[8];
    const float* w_root3 = (const float*)d_in[9];
    const float* b3      = (const float*)d_in[10];
    float* out = (float*)d_out;

    const int N = in_sizes[0] / 128;
    const int E = in_sizes[1] / 2;
    const int* src = ei;
    const int* dst = ei + E;

    // workspace layout (~84 MB)
    char* w = (char*)d_ws;
    auto alloc = [&](size_t bytes) {
        char* p = w;
        w += (bytes + 255) & ~(size_t)255;
        return p;
    };
    int*  col  = (int*)alloc((size_t)E * 4);            // 6.4 MB
    int*  rp   = (int*)alloc((size_t)(N + 1) * 4);      // 0.4 MB
    bf16* h1   = (bf16*)alloc((size_t)N * 128 * 2);     // 25.6 MB
    bf16* xbf  = (bf16*)alloc((size_t)N * 128 * 2);     // 25.6 MB (reused as h2)
    bf16* agg  = (bf16*)alloc((size_t)N * 128 * 2);     // 25.6 MB
    bf16* wsw1 = (bf16*)alloc(32768 * 2);               // 64 KB
    bf16* wsw2 = (bf16*)alloc(32768 * 2);
    bf16* wsw3 = (bf16*)alloc(32768 * 2);
    bf16* h2   = xbf;       // layer-2 output overwrites xbf (last read: layer-1 gemm)
    // CSR-build scratch aliases buffers written only AFTER the build completes:
    int*  T    = (int*)h1;                  // NB*GB ints (~306 KB) in h1's space
    int*  bsum = (int*)(h1 + 1024 * 1024);  // scan partials, past T
    int*  ebuf = (int*)agg;                 // E ints (6.4 MB) in agg's space

    const int NB = (N + BSZ - 1) / BSZ;        // 391 buckets
    const int GB = (E + CHUNK - 1) / CHUNK;    // 196 sort blocks
    const int nT = NB * GB;                    // 76,636
    const int scanTBlocks = (nT + 255) / 256;  // 300 <= 512

    const int aggBlocks  = (N + 3) / 4;
    const int gemmBlocks = (N + 63) / 64;
    const int cvtBlocks  = (N * 32 + 255) / 256;

    // prep: x -> bf16, weights -> swizzled bf16 B-fragments
    cvt_kernel<<<cvtBlocks, 256, 0, stream>>>(x, xbf, N * 32);
    prep_w_kernel<<<16, 256, 0, stream>>>(w_rel1, w_root1, wsw1);
    prep_w_kernel<<<16, 256, 0, stream>>>(w_rel2, w_root2, wsw2);
    prep_w_kernel<<<16, 256, 0, stream>>>(w_rel3, w_root3, wsw3);

    // CSR by dst: two-level counting sort (no global atomics, no memsets)
    bhist_kernel<<<GB, 256, 0, stream>>>(dst, T, E, NB, GB);
    scan1_kernel<<<scanTBlocks, 256, 0, stream>>>(T, T, bsum, nT);
    scan2_kernel<<<1, 512, 0, stream>>>(bsum, scanTBlocks);
    scan3_kernel<<<scanTBlocks, 256, 0, stream>>>(T, bsum, nT);
    bscatter_kernel<<<GB, 256, 0, stream>>>(src, dst, T, ebuf, E, NB, GB);
    bbuild_kernel<<<NB, 256, 0, stream>>>(T, ebuf, rp, col, E, N, NB, GB);

    // layer 1
    agg_kernel<<<aggBlocks, 256, 0, stream>>>(xbf, rp, col, agg, N);
    mfma_gemm_kernel<true, bf16><<<gemmBlocks, 256, 0, stream>>>(agg, xbf, wsw1, b1, h1, N);
    // layer 2
    agg_kernel<<<aggBlocks, 256, 0, stream>>>(h1, rp, col, agg, N);
    mfma_gemm_kernel<true, bf16><<<gemmBlocks, 256, 0, stream>>>(agg, h1, wsw2, b2, h2, N);
    // layer 3
    agg_kernel<<<aggBlocks, 256, 0, stream>>>(h2, rp, col, agg, N);
    mfma_gemm_kernel<false, float><<<gemmBlocks, 256, 0, stream>>>(agg, h2, wsw3, b3, out, N);
}